// Round 2
// baseline (232.473 us; speedup 1.0000x reference)
//
#include <hip/hip_runtime.h>

#define BB 16
#define PP 96
#define TT 128
#define VV 64
#define NN 16
#define DD 128
#define BPP (BB * PP)     // 1536 attention blocks
#define NPASS (BB * 32)   // 512 passthrough blocks
#define SB 136            // bf16 row stride for q/Ks/O tiles (272 B)
#define ST 72             // KsT / A row stride (144 B)
#define SSF 68            // S f32 row stride (272 B = same bytes as SB)
#define SCALE 0.08838834764831845f
#define SLICE 4352        // per-wave byte slice in region1 (= 16 rows * 272 B)

typedef __bf16 bf16x8 __attribute__((ext_vector_type(8)));
typedef __bf16 bf16x4 __attribute__((ext_vector_type(4)));
typedef float  floatx4 __attribute__((ext_vector_type(4)));
typedef unsigned int uint32x4 __attribute__((ext_vector_type(4)));

#define MFMA16(a, b, c) __builtin_amdgcn_mfma_f32_16x16x32_bf16(a, b, c, 0, 0, 0)

__device__ __forceinline__ bf16x8 cvt8(float4 a, float4 b) {
    return bf16x8{(__bf16)a.x, (__bf16)a.y, (__bf16)a.z, (__bf16)a.w,
                  (__bf16)b.x, (__bf16)b.y, (__bf16)b.z, (__bf16)b.w};
}

// A-frags for a 16-row strip directly from global f32 (row stride DD).
__device__ __forceinline__ void loadA_g(const float* Xs, int lm, int lq, bf16x8 af[4]) {
    const float4* p = (const float4*)(Xs + lm * DD + lq * 8);
#pragma unroll
    for (int ks = 0; ks < 4; ++ks) af[ks] = cvt8(p[8 * ks], p[8 * ks + 1]);
}

// A-frags from LDS bf16 (row stride sa), kblocks k-chunks of 32
__device__ __forceinline__ void loadA_l(const __bf16* As, int sa, int lm, int lq,
                                        bf16x8* af, int kblocks) {
#pragma unroll
    for (int ks = 0; ks < 4; ++ks) {
        if (ks >= kblocks) break;
        af[ks] = *(const bf16x8*)(As + lm * sa + lq * 8 + 32 * ks);
    }
}

// acc[nb] = A_strip @ B^T ; B row-major bf16 stride sb (global weights or LDS)
__device__ __forceinline__ void mmB(const bf16x8* af, const __bf16* B, int sb,
                                    int lm, int lq, floatx4* acc, int nblocks, int kblocks) {
#pragma unroll
    for (int nb = 0; nb < 8; ++nb) {
        if (nb >= nblocks) break;
        acc[nb] = floatx4{0.f, 0.f, 0.f, 0.f};
#pragma unroll
        for (int ks = 0; ks < 4; ++ks) {
            if (ks >= kblocks) break;
            bf16x8 bf = *(const bf16x8*)(B + (nb * 16 + lm) * sb + lq * 8 + 32 * ks);
            acc[nb] = MFMA16(af[ks], bf, acc[nb]);
        }
    }
}

// ---------------------------------------------------------------------------
// prep: Wb = bf16{Wq | Wkv | Wout | Wcomb=Wout@Wkv}; bcomb = Wout@bkv + bout
// ---------------------------------------------------------------------------
__global__ void prep(const float* __restrict__ Wq, const float* __restrict__ Wkv,
                     const float* __restrict__ Wout, const float* __restrict__ bkv,
                     const float* __restrict__ bout,
                     __bf16* __restrict__ Wb, float* __restrict__ bcomb) {
    int i = blockIdx.x, j = threadIdx.x;
    Wb[i * DD + j]         = (__bf16)Wq[i * DD + j];
    Wb[16384 + i * DD + j] = (__bf16)Wkv[i * DD + j];
    Wb[32768 + i * DD + j] = (__bf16)Wout[i * DD + j];
    float acc = 0.f;
    for (int k = 0; k < DD; ++k) acc += Wout[i * DD + k] * Wkv[k * DD + j];
    Wb[49152 + i * DD + j] = (__bf16)acc;
    if (i == 0) {
        float bs = bout[j];
        for (int k = 0; k < DD; ++k) bs += Wout[j * DD + k] * bkv[k];
        bcomb[j] = bs;
    }
}

// ---------------------------------------------------------------------------
// fused: blocks [0,1536) = attention per (b,p); [1536,2048) = passthrough.
// 4 waves; wave w owns output rows [16w,16w+16). ONE barrier per block.
// K-first phase order keeps qr/kr from being co-resident (VGPR peak under
// the launch_bounds(256,3) cap of 168): P0k -> P2(Ks) -> issue q/se loads
// -> Ks stores -> barrier -> P1(q, wave-private) -> P3..P6.
// ---------------------------------------------------------------------------
__global__ __launch_bounds__(256, 3) void fused(
    const float* __restrict__ queries, const float* __restrict__ keys,
    const int* __restrict__ ccc, const __bf16* __restrict__ Wb,
    const float* __restrict__ bq, const float* __restrict__ bkv,
    const float* __restrict__ bout, const float* __restrict__ bcomb,
    float* __restrict__ out) {
    __shared__ __align__(16) char lds[53248];
    __bf16* R1    = (__bf16*)lds;             // 17408: q / S(f32) / A / O (per-wave slices)
    __bf16* smKs  = (__bf16*)(lds + 17408);   // 17408: Ks row-major
    __bf16* smKsT = (__bf16*)(lds + 34816);   // 18432: Ks^T (128 x 64)
    float*  smS   = (float*)lds;

    int bl = blockIdx.x, t = threadIdx.x;
    int w = t >> 6, L = t & 63, lm = L & 15, lq = L >> 4;

    bf16x8 af[4];
    floatx4 acc[8];

    if (bl >= BPP) {
        // ---- passthrough: out[b, wi rows] = keys @ Wcomb^T + bcomb ----
        int pb = bl - BPP;
        int b = pb >> 5, wi = pb & 31;
        const float* Xs = keys + ((long)b * TT * VV + wi * 64 + w * 16) * DD;
        float* Yg = out + ((long)b * TT * VV + wi * 64) * DD;
        loadA_g(Xs, lm, lq, af);
        mmB(af, Wb + 49152, DD, lm, lq, acc, 8, 4);
#pragma unroll
        for (int nb = 0; nb < 8; ++nb) {
            float bv = bcomb[nb * 16 + lm];
#pragma unroll
            for (int r = 0; r < 4; ++r)
                Yg[(long)(w * 16 + lq * 4 + r) * DD + nb * 16 + lm] = acc[nb][r] + bv;
        }
        return;
    }

    int b = bl / PP, p = bl % PP;
    const float* Qg = queries + ((long)(b * PP + p) * VV) * DD;
    const float* Kg = keys + ((long)(b * TT + 32 + p) * VV) * DD;
    float* Yg = out + ((long)(b * TT + 32 + p) * VV) * DD;

    // ---- P0k: K strip loads only (qr NOT live here) ----
    float4 kr[8];
    {
        const float4* kp = (const float4*)(Kg + (w * 16 + lm) * DD + lq * 8);
#pragma unroll
        for (int ks = 0; ks < 4; ++ks) {
            kr[2 * ks] = kp[8 * ks]; kr[2 * ks + 1] = kp[8 * ks + 1];
        }
    }

    // ---- P2: Ks = K @ Wkv^T + bkv (MFMAs first; stores below) ----
#pragma unroll
    for (int ks = 0; ks < 4; ++ks) af[ks] = cvt8(kr[2 * ks], kr[2 * ks + 1]);
    mmB(af, Wb + 16384, DD, lm, lq, acc, 8, 4);

    // ---- issue Q strip loads now: HBM latency hides under Ks stores + barrier
    float4 qr[8];
    {
        const float4* qp = (const float4*)(Qg + (w * 16 + lm) * DD + lq * 8);
#pragma unroll
        for (int ks = 0; ks < 4; ++ks) {
            qr[2 * ks] = qp[8 * ks]; qr[2 * ks + 1] = qp[8 * ks + 1];
        }
    }

    // ---- Ks stores -> smKs + smKsT ----
#pragma unroll
    for (int nb = 0; nb < 8; ++nb) {
        float bv = bkv[nb * 16 + lm];
        bf16x4 tp;
#pragma unroll
        for (int r = 0; r < 4; ++r) {
            float vv = acc[nb][r] + bv;
            smKs[(w * 16 + lq * 4 + r) * SB + nb * 16 + lm] = (__bf16)vv;
            tp[r] = (__bf16)vv;
        }
        *(bf16x4*)(smKsT + (nb * 16 + lm) * ST + w * 16 + lq * 4) = tp;
    }

    // ---- ccc row loads (L2-hot, consumed in P4) ----
    int se[NN];
    {
        const int4* cp = (const int4*)(ccc + ((long)b * VV + w * 16 + lm) * NN);
#pragma unroll
        for (int i = 0; i < 4; ++i) {
            int4 c4 = cp[i];
            se[4 * i] = c4.x; se[4 * i + 1] = c4.y;
            se[4 * i + 2] = c4.z; se[4 * i + 3] = c4.w;
        }
    }
    __syncthreads();  // B1: publish Ks/KsT (the ONLY barrier)

    // ---- P1: q = Q @ Wq^T + bq -> q strip (wave-private slice, post-barrier ok) ----
#pragma unroll
    for (int ks = 0; ks < 4; ++ks) af[ks] = cvt8(qr[2 * ks], qr[2 * ks + 1]);
    mmB(af, Wb, DD, lm, lq, acc, 8, 4);
#pragma unroll
    for (int nb = 0; nb < 8; ++nb) {
        float bv = bq[nb * 16 + lm];
#pragma unroll
        for (int r = 0; r < 4; ++r)
            R1[(w * 16 + lq * 4 + r) * SB + nb * 16 + lm] = (__bf16)(acc[nb][r] + bv);
    }

    // ---- P3: S = q @ Ks^T (f32) -> S strip over q slice (af read first) ----
    loadA_l(R1 + w * 16 * SB, SB, lm, lq, af, 4);
    mmB(af, smKs, SB, lm, lq, acc, 4, 4);
#pragma unroll
    for (int nb = 0; nb < 4; ++nb)
#pragma unroll
        for (int r = 0; r < 4; ++r)
            smS[(w * 16 + lq * 4 + r) * SSF + nb * 16 + lm] = acc[nb][r];

    // ---- P4: softmax + dup-total scatter, all 64 lanes, no RMW, no barrier ----
    __bf16* smAsl = (__bf16*)(lds + w * SLICE);  // A strip: 16 rows x ST bf16
    {
        int g = lq;  // lane handles row lm, n-quad g
        float sg[NN];
        const float* Srow = smS + (w * 16 + lm) * SSF;
#pragma unroll
        for (int n = 0; n < NN; ++n) sg[n] = Srow[se[n]];  // reads issued first
        __builtin_amdgcn_sched_barrier(0);  // keep A-strip zeroing after S gather (regions alias)
        // zero A strip cols [0,64): lane L zeroes row L>>2, bytes (L&3)*32 .. +32
        // (two b128 writes; 64 lanes x 32 B = 16 rows x 128 B exactly)
        {
            uint32x4 z{0u, 0u, 0u, 0u};
            char* zb = (char*)smAsl + (L >> 2) * (ST * 2) + (L & 3) * 32;
            *(uint32x4*)zb = z;
            *(uint32x4*)(zb + 16) = z;
        }
        float mx = -1e30f;
#pragma unroll
        for (int n = 0; n < NN; ++n) { sg[n] *= SCALE; mx = fmaxf(mx, sg[n]); }
        float sum = 0.f;
#pragma unroll
        for (int n = 0; n < NN; ++n) { sg[n] = __expf(sg[n] - mx); sum += sg[n]; }
        float inv = 1.f / sum;
#pragma unroll
        for (int j = 0; j < 4; ++j) {  // dup groups write identical totals
            int u = se[g * 4 + j];
            float tot = 0.f;
#pragma unroll
            for (int n = 0; n < NN; ++n) tot += (se[n] == u) ? sg[n] : 0.f;
            smAsl[lm * ST + u] = (__bf16)(tot * inv);
        }
    }

    // ---- P5: O = A_sp @ Ks (B from KsT), K=64 -> O strip over slice ----
    loadA_l(smAsl, ST, lm, lq, af, 2);
    mmB(af, smKsT, ST, lm, lq, acc, 8, 2);
#pragma unroll
    for (int nb = 0; nb < 8; ++nb)
#pragma unroll
        for (int r = 0; r < 4; ++r)
            R1[(w * 16 + lq * 4 + r) * SB + nb * 16 + lm] = (__bf16)acc[nb][r];

    // ---- P6: Y = O @ Wout^T + bout -> global (same-wave strip) ----
    loadA_l(R1 + w * 16 * SB, SB, lm, lq, af, 4);
    mmB(af, Wb + 32768, DD, lm, lq, acc, 8, 4);
#pragma unroll
    for (int nb = 0; nb < 8; ++nb) {
        float bv = bout[nb * 16 + lm];
#pragma unroll
        for (int r = 0; r < 4; ++r)
            Yg[(long)(w * 16 + lq * 4 + r) * DD + nb * 16 + lm] = acc[nb][r] + bv;
    }
}

extern "C" void kernel_launch(void* const* d_in, const int* in_sizes, int n_in,
                              void* d_out, int out_size, void* d_ws, size_t ws_size,
                              hipStream_t stream) {
    const float* queries = (const float*)d_in[0];
    const float* keys    = (const float*)d_in[1];
    const int*   ccc     = (const int*)d_in[2];
    const float* Wq      = (const float*)d_in[3];
    const float* bq      = (const float*)d_in[4];
    const float* Wkv     = (const float*)d_in[5];
    const float* bkv     = (const float*)d_in[6];
    const float* Wout    = (const float*)d_in[7];
    const float* bout    = (const float*)d_in[8];
    float* out = (float*)d_out;

    __bf16* Wb    = (__bf16*)d_ws;                        // 4 x 16384 bf16 = 128 KB
    float*  bcomb = (float*)((char*)d_ws + 131072);       // 128 f32

    prep<<<dim3(128), dim3(128), 0, stream>>>(Wq, Wkv, Wout, bkv, bout, Wb, bcomb);

    fused<<<dim3(BPP + NPASS), dim3(256), 0, stream>>>(
        queries, keys, ccc, Wb, bq, bkv, bout, bcomb, out);
}

// Round 3
// 225.585 us; speedup vs baseline: 1.0305x; 1.0305x over previous
//
#include <hip/hip_runtime.h>

#define BB 16
#define PP 96
#define TT 128
#define VV 64
#define NN 16
#define DD 128
#define BPP (BB * PP)     // 1536 attention blocks
#define NPASS (BB * 32)   // 512 passthrough blocks
#define SB 136            // bf16 row stride for qW/K tiles (272 B)
#define ST 72             // KCT / A row stride (144 B)
#define SSF 68            // S f32 row stride (272 B = same bytes as SB)
#define SCALE 0.08838834764831845f
#define SLICE 4352        // per-wave byte slice in region1 (= 16 rows * 272 B)

typedef __bf16 bf16x8 __attribute__((ext_vector_type(8)));
typedef __bf16 bf16x4 __attribute__((ext_vector_type(4)));
typedef float  floatx4 __attribute__((ext_vector_type(4)));
typedef unsigned int uint32x4 __attribute__((ext_vector_type(4)));

#define MFMA16(a, b, c) __builtin_amdgcn_mfma_f32_16x16x32_bf16(a, b, c, 0, 0, 0)

__device__ __forceinline__ bf16x8 cvt8(float4 a, float4 b) {
    return bf16x8{(__bf16)a.x, (__bf16)a.y, (__bf16)a.z, (__bf16)a.w,
                  (__bf16)b.x, (__bf16)b.y, (__bf16)b.z, (__bf16)b.w};
}

// A-frags for a 16-row strip directly from global f32 (row stride DD).
__device__ __forceinline__ void loadA_g(const float* Xs, int lm, int lq, bf16x8 af[4]) {
    const float4* p = (const float4*)(Xs + lm * DD + lq * 8);
#pragma unroll
    for (int ks = 0; ks < 4; ++ks) af[ks] = cvt8(p[8 * ks], p[8 * ks + 1]);
}

// A-frags from LDS bf16 (row stride sa), kblocks k-chunks of 32
__device__ __forceinline__ void loadA_l(const __bf16* As, int sa, int lm, int lq,
                                        bf16x8* af, int kblocks) {
#pragma unroll
    for (int ks = 0; ks < 4; ++ks) {
        if (ks >= kblocks) break;
        af[ks] = *(const bf16x8*)(As + lm * sa + lq * 8 + 32 * ks);
    }
}

// acc[nb] = A_strip @ B^T ; B row-major bf16 stride sb (global weights or LDS)
__device__ __forceinline__ void mmB(const bf16x8* af, const __bf16* B, int sb,
                                    int lm, int lq, floatx4* acc, int nblocks, int kblocks) {
#pragma unroll
    for (int nb = 0; nb < 8; ++nb) {
        if (nb >= nblocks) break;
        acc[nb] = floatx4{0.f, 0.f, 0.f, 0.f};
#pragma unroll
        for (int ks = 0; ks < 4; ++ks) {
            if (ks >= kblocks) break;
            bf16x8 bf = *(const bf16x8*)(B + (nb * 16 + lm) * sb + lq * 8 + 32 * ks);
            acc[nb] = MFMA16(af[ks], bf, acc[nb]);
        }
    }
}

// ---------------------------------------------------------------------------
// prep: Wb = bf16{ M1 = (Wq^T Wkv)^T  |  Wcomb = Wout@Wkv };
//       bcomb = Wout@bkv + bout ; bqk = bq@Wkv
// Score path: S = (Q@M1^T)@K^T  (the row-constant q.bkv term is
// softmax-invariant and dropped). Output path: Y = A@(K@Wcomb^T) + bcomb.
// ---------------------------------------------------------------------------
__global__ void prep(const float* __restrict__ Wq, const float* __restrict__ Wkv,
                     const float* __restrict__ Wout, const float* __restrict__ bq,
                     const float* __restrict__ bkv, const float* __restrict__ bout,
                     __bf16* __restrict__ Wb, float* __restrict__ bcomb,
                     float* __restrict__ bqk) {
    int i = blockIdx.x, j = threadIdx.x;
    float m1 = 0.f, wc = 0.f;
    for (int k = 0; k < DD; ++k) {
        m1 += Wq[k * DD + j] * Wkv[k * DD + i];    // M1[i][j] = sum_k Wq[k][j] Wkv[k][i]
        wc += Wout[i * DD + k] * Wkv[k * DD + j];  // Wcomb[i][j]
    }
    Wb[i * DD + j]         = (__bf16)m1;
    Wb[16384 + i * DD + j] = (__bf16)wc;
    if (i == 0) {
        float bs = bout[j], bk = 0.f;
        for (int k = 0; k < DD; ++k) {
            bs += Wout[j * DD + k] * bkv[k];
            bk += bq[k] * Wkv[k * DD + j];
        }
        bcomb[j] = bs;
        bqk[j] = bk;
    }
}

// ---------------------------------------------------------------------------
// fused: blocks [0,1536) = attention per (b,p); [1536,2048) = passthrough.
// 4 waves; wave w owns rows [16w,16w+16). ONE barrier per block.
// Pre-barrier:  K loads -> KC = K@Wcomb^T (regs) -> {smK raw-K store,
//               KCT transpose-scatter} ; Q loads -> qW = Q@M1^T -> R1 slice.
// Post-barrier: S = qW@K^T -> softmax/dup-scatter -> Y = A@KC + bcomb -> HBM.
// ---------------------------------------------------------------------------
__global__ __launch_bounds__(256, 3) void fused(
    const float* __restrict__ queries, const float* __restrict__ keys,
    const int* __restrict__ ccc, const __bf16* __restrict__ Wb,
    const float* __restrict__ bqk, const float* __restrict__ bcomb,
    float* __restrict__ out) {
    __shared__ __align__(16) char lds[53248];
    __bf16* R1    = (__bf16*)lds;             // 17408: qW / S(f32) / A (per-wave slices)
    __bf16* smK   = (__bf16*)(lds + 17408);   // 17408: raw K bf16, row-major 64 x 128
    __bf16* smKCT = (__bf16*)(lds + 34816);   // 18432: (K@Wcomb^T)^T, 128 x 64
    float*  smS   = (float*)lds;

    int bl = blockIdx.x, t = threadIdx.x;
    int w = t >> 6, L = t & 63, lm = L & 15, lq = L >> 4;

    bf16x8 af[4];
    floatx4 acc[8];

    if (bl >= BPP) {
        // ---- passthrough: out[b, wi rows] = keys @ Wcomb^T + bcomb ----
        int pb = bl - BPP;
        int b = pb >> 5, wi = pb & 31;
        const float* Xs = keys + ((long)b * TT * VV + wi * 64 + w * 16) * DD;
        float* Yg = out + ((long)b * TT * VV + wi * 64) * DD;
        loadA_g(Xs, lm, lq, af);
        mmB(af, Wb + 16384, DD, lm, lq, acc, 8, 4);
#pragma unroll
        for (int nb = 0; nb < 8; ++nb) {
            float bv = bcomb[nb * 16 + lm];
#pragma unroll
            for (int r = 0; r < 4; ++r)
                Yg[(long)(w * 16 + lq * 4 + r) * DD + nb * 16 + lm] = acc[nb][r] + bv;
        }
        return;
    }

    int b = bl / PP, p = bl % PP;
    const float* Qg = queries + ((long)(b * PP + p) * VV) * DD;
    const float* Kg = keys + ((long)(b * TT + 32 + p) * VV) * DD;
    float* Yg = out + ((long)(b * TT + 32 + p) * VV) * DD;

    // ---- P0k: K strip loads (qr NOT live here) ----
    float4 kr[8];
    {
        const float4* kp = (const float4*)(Kg + (w * 16 + lm) * DD + lq * 8);
#pragma unroll
        for (int ks = 0; ks < 4; ++ks) {
            kr[2 * ks] = kp[8 * ks]; kr[2 * ks + 1] = kp[8 * ks + 1];
        }
    }

    // ---- KC = K @ Wcomb^T (no bias; bcomb added in the epilogue) ----
#pragma unroll
    for (int ks = 0; ks < 4; ++ks) af[ks] = cvt8(kr[2 * ks], kr[2 * ks + 1]);
    mmB(af, Wb + 16384, DD, lm, lq, acc, 8, 4);

    // ---- issue Q strip loads: HBM latency hides under the scatters + barrier
    float4 qr[8];
    {
        const float4* qp = (const float4*)(Qg + (w * 16 + lm) * DD + lq * 8);
#pragma unroll
        for (int ks = 0; ks < 4; ++ks) {
            qr[2 * ks] = qp[8 * ks]; qr[2 * ks + 1] = qp[8 * ks + 1];
        }
    }

    // ---- raw-K store: af[ks] IS K[16w+lm][32ks+8lq .. +7] in bf16 ----
#pragma unroll
    for (int ks = 0; ks < 4; ++ks)
        *(bf16x8*)(smK + (w * 16 + lm) * SB + lq * 8 + 32 * ks) = af[ks];

    // ---- KCT transpose-scatter (C-layout -> 128 d-rows x 64 keys) ----
#pragma unroll
    for (int nb = 0; nb < 8; ++nb) {
        bf16x4 tp;
#pragma unroll
        for (int r = 0; r < 4; ++r) tp[r] = (__bf16)acc[nb][r];
        *(bf16x4*)(smKCT + (nb * 16 + lm) * ST + w * 16 + lq * 4) = tp;
    }

    // ---- qW = Q @ M1^T + bqk -> R1 slice (wave-private) ----
#pragma unroll
    for (int ks = 0; ks < 4; ++ks) af[ks] = cvt8(qr[2 * ks], qr[2 * ks + 1]);
    mmB(af, Wb, DD, lm, lq, acc, 8, 4);
#pragma unroll
    for (int nb = 0; nb < 8; ++nb) {
        float bv = bqk[nb * 16 + lm];
#pragma unroll
        for (int r = 0; r < 4; ++r)
            R1[(w * 16 + lq * 4 + r) * SB + nb * 16 + lm] = (__bf16)(acc[nb][r] + bv);
    }

    // ---- ccc row loads (L2-hot, consumed in P4) ----
    int se[NN];
    {
        const int4* cp = (const int4*)(ccc + ((long)b * VV + w * 16 + lm) * NN);
#pragma unroll
        for (int i = 0; i < 4; ++i) {
            int4 c4 = cp[i];
            se[4 * i] = c4.x; se[4 * i + 1] = c4.y;
            se[4 * i + 2] = c4.z; se[4 * i + 3] = c4.w;
        }
    }
    __syncthreads();  // B1: publish smK/smKCT (the ONLY barrier)

    // ---- P3: S = qW @ K^T (f32) -> S strip over the qW slice ----
    loadA_l(R1 + w * 16 * SB, SB, lm, lq, af, 4);
    mmB(af, smK, SB, lm, lq, acc, 4, 4);
#pragma unroll
    for (int nb = 0; nb < 4; ++nb)
#pragma unroll
        for (int r = 0; r < 4; ++r)
            smS[(w * 16 + lq * 4 + r) * SSF + nb * 16 + lm] = acc[nb][r];

    // ---- P4: softmax + dup-total scatter, all 64 lanes, no RMW, no barrier ----
    __bf16* smAsl = (__bf16*)(lds + w * SLICE);  // A strip: 16 rows x ST bf16
    {
        int g = lq;  // lane handles row lm, n-quad g
        float sg[NN];
        const float* Srow = smS + (w * 16 + lm) * SSF;
#pragma unroll
        for (int n = 0; n < NN; ++n) sg[n] = Srow[se[n]];  // reads issued first
        __builtin_amdgcn_sched_barrier(0);  // keep A-strip zeroing after S gather (regions alias)
        // zero A strip cols [0,64): lane L zeroes row L>>2, bytes (L&3)*32 .. +32
        {
            uint32x4 z{0u, 0u, 0u, 0u};
            char* zb = (char*)smAsl + (L >> 2) * (ST * 2) + (L & 3) * 32;
            *(uint32x4*)zb = z;
            *(uint32x4*)(zb + 16) = z;
        }
        float mx = -1e30f;
#pragma unroll
        for (int n = 0; n < NN; ++n) { sg[n] *= SCALE; mx = fmaxf(mx, sg[n]); }
        float sum = 0.f;
#pragma unroll
        for (int n = 0; n < NN; ++n) { sg[n] = __expf(sg[n] - mx); sum += sg[n]; }
        float inv = 1.f / sum;
#pragma unroll
        for (int j = 0; j < 4; ++j) {  // dup groups write identical totals
            int u = se[g * 4 + j];
            float tot = 0.f;
#pragma unroll
            for (int n = 0; n < NN; ++n) tot += (se[n] == u) ? sg[n] : 0.f;
            smAsl[lm * ST + u] = (__bf16)(tot * inv);
        }
    }

    // ---- P5: Y = A @ KC + bcomb (B from KCT), K=64 -> global directly ----
    loadA_l(smAsl, ST, lm, lq, af, 2);
    mmB(af, smKCT, ST, lm, lq, acc, 8, 2);
#pragma unroll
    for (int nb = 0; nb < 8; ++nb) {
        float bv = bcomb[nb * 16 + lm];
#pragma unroll
        for (int r = 0; r < 4; ++r)
            Yg[(long)(w * 16 + lq * 4 + r) * DD + nb * 16 + lm] = acc[nb][r] + bv;
    }
}

extern "C" void kernel_launch(void* const* d_in, const int* in_sizes, int n_in,
                              void* d_out, int out_size, void* d_ws, size_t ws_size,
                              hipStream_t stream) {
    const float* queries = (const float*)d_in[0];
    const float* keys    = (const float*)d_in[1];
    const int*   ccc     = (const int*)d_in[2];
    const float* Wq      = (const float*)d_in[3];
    const float* bq      = (const float*)d_in[4];
    const float* Wkv     = (const float*)d_in[5];
    const float* bkv     = (const float*)d_in[6];
    const float* Wout    = (const float*)d_in[7];
    const float* bout    = (const float*)d_in[8];
    float* out = (float*)d_out;

    __bf16* Wb    = (__bf16*)d_ws;                        // 2 x 16384 bf16 = 64 KB
    float*  bcomb = (float*)((char*)d_ws + 65536);        // 128 f32
    float*  bqk   = (float*)((char*)d_ws + 66048);        // 128 f32

    prep<<<dim3(128), dim3(128), 0, stream>>>(Wq, Wkv, Wout, bq, bkv, bout, Wb, bcomb, bqk);

    fused<<<dim3(BPP + NPASS), dim3(256), 0, stream>>>(
        queries, keys, ccc, Wb, bqk, bcomb, out);
}